// Round 11
// baseline (19.158 us; speedup 1.0000x reference)
//
#include <hip/hip_runtime.h>

#define NSEQ 4096
#define DIM  256
#define WIN  128
#define BATCH 4

typedef __bf16 bf16x8 __attribute__((ext_vector_type(8)));
typedef float  f32x4  __attribute__((ext_vector_type(4)));
typedef int    v2i    __attribute__((ext_vector_type(2)));
typedef int    v4i    __attribute__((ext_vector_type(4)));

// subtiled layout: element (j,d) of a 32x256 tile at
// ((j>>2)*16 + (d>>4))*64 + (j&3)*16 + (d&15)  halfwords. (verified r2/r6)
__device__ __forceinline__ int sub_off(int j, int d) {
    return (((j >> 2) * 16 + (d >> 4)) << 6) + ((j & 3) << 4) + (d & 15);
}

// HW packed f32->bf16 (RNE)
__device__ __forceinline__ unsigned pk2bf(float lo, float hi) {
    unsigned r;
    asm("v_cvt_pk_bf16_f32 %0, %1, %2" : "=v"(r) : "v"(lo), "v"(hi));
    return r;
}

__global__ __launch_bounds__(256, 3)
void sp_kernel(const float* __restrict__ val,
               const float* __restrict__ state,
               float* __restrict__ out) {
    __shared__ __align__(128) unsigned short vbuf[2][8192];  // 32 KB double buffer

    // XCD-aware bijective swizzle (512 = 8*64)
    const int bx  = blockIdx.x;
    const int lbx = ((bx & 7) << 6) + (bx >> 3);
    const int b      = lbx >> 7;
    const int tile_i = lbx & 127;
    const int r0     = tile_i << 5;

    const int t   = threadIdx.x;
    const int w   = t >> 6;
    const int l   = t & 63;
    const int l15 = l & 15;
    const int l4  = l >> 4;
    const int mt  = w >> 1;            // i-half this wave owns (0..1)
    const int jt  = w & 1;             // d-half this wave owns for PV (0..1)

    const float* valb = val + ((size_t)b * NSEQ) * DIM;
    const float* stb  = state + ((size_t)b * NSEQ);
    float* out_state  = out + ((size_t)b * NSEQ);
    float* out_val    = out + (size_t)BATCH * NSEQ + ((size_t)b * NSEQ) * DIM;

    // staging row pattern (verified conflict-free)
    const int s_jl0 = (w << 2) + l4;
    const int s_jl1 = s_jl0 + 16;

    // ---- prologue: stage tile_i into vbuf[0] ----
    {
        const float* src = valb + ((size_t)tile_i << 13);
        #pragma unroll
        for (int qq = 0; qq < 8; ++qq) {
            const int jl = (qq & 1) ? s_jl1 : s_jl0;
            const int d0 = (l15 << 2) + ((qq >> 1) << 6);
            float4 v = *reinterpret_cast<const float4*>(src + jl * DIM + d0);
            uint2 u;
            u.x = pk2bf(v.x, v.y);
            u.y = pk2bf(v.z, v.w);
            *reinterpret_cast<uint2*>(&vbuf[0][sub_off(jl, d0)]) = u;
        }
    }
    __syncthreads();

    // ---- af: Vi rows (PV-independent B-operand of swapped scores), i = mt*16+l15 ----
    const int il = (mt << 4) + l15;
    bf16x8 af[8];
    #pragma unroll
    for (int ks = 0; ks < 8; ++ks)
        af[ks] = *reinterpret_cast<const bf16x8*>(&vbuf[0][sub_off(il, (l4 << 3) + (ks << 5))]);

    const int tj0   = (tile_i >= 4) ? (tile_i - 4) : 0;
    const int ntile = tile_i - tj0 + 1;
    const int ig    = r0 + (mt << 4) + l15;   // this lane's output row (fixed)

    float dsacc = 0.f;
    f32x4 accpv[8];
    #pragma unroll
    for (int u = 0; u < 8; ++u)
        accpv[u] = (f32x4){0.f, 0.f, 0.f, 0.f};

    int p = 0;
    for (int q = 0; q < ntile; ++q) {
        const int ti = tile_i - q;
        const bool havenext = (q + 1 < ntile);
        const unsigned short* bp = &vbuf[p][0];
        unsigned short* bn = &vbuf[1 - p][0];

        // ---- stage next tile (inline load+cvt+write; compiler overlaps with below) ----
        if (havenext) {
            const float* src = valb + ((size_t)(ti - 1) << 13);
            #pragma unroll
            for (int qq = 0; qq < 8; ++qq) {
                const int jl2 = (qq & 1) ? s_jl1 : s_jl0;
                const int d0  = (l15 << 2) + ((qq >> 1) << 6);
                float4 v = *reinterpret_cast<const float4*>(src + jl2 * DIM + d0);
                uint2 u;
                u.x = pk2bf(v.x, v.y);
                u.y = pk2bf(v.z, v.w);
                *reinterpret_cast<uint2*>(&bn[sub_off(jl2, d0)]) = u;
            }
        }

        // ---- swapped scores: S^T = Vj * Vi^T; lane gets E[i=ig][j = h*16 + l4*4 + r] ----
        bf16x8 sb0[8], sb1[8];
        #pragma unroll
        for (int ks = 0; ks < 8; ++ks) {
            sb0[ks] = *reinterpret_cast<const bf16x8*>(&bp[sub_off(l15,      (l4 << 3) + (ks << 5))]);
            sb1[ks] = *reinterpret_cast<const bf16x8*>(&bp[sub_off(16 + l15, (l4 << 3) + (ks << 5))]);
        }
        f32x4 a0 = (f32x4){0.f, 0.f, 0.f, 0.f};
        f32x4 a1 = (f32x4){0.f, 0.f, 0.f, 0.f};
        #pragma unroll
        for (int ks = 0; ks < 8; ++ks) {
            a0 = __builtin_amdgcn_mfma_f32_16x16x32_bf16(sb0[ks], af[ks], a0, 0, 0, 0);
            a1 = __builtin_amdgcn_mfma_f32_16x16x32_bf16(sb1[ks], af[ks], a1, 0, 0, 0);
        }

        // ---- edges in-register: scale, softsign, mask; dsacc; pack to PV A-frag ----
        const int jb = ti << 5;
        const float4 st0 = *reinterpret_cast<const float4*>(stb + jb + (l4 << 2));
        const float4 st1 = *reinterpret_cast<const float4*>(stb + jb + 16 + (l4 << 2));
        float e0[4], e1[4];
        #pragma unroll
        for (int r = 0; r < 4; ++r) {
            const int jg0 = jb + (l4 << 2) + r;
            float s = a0[r] * 0.0625f;
            float e = s * __builtin_amdgcn_rcpf(1.0f + fabsf(s));
            if (jg0 > ig || jg0 < ig - WIN) e = 0.0f;
            e0[r] = e;
            const int jg1 = jg0 + 16;
            s = a1[r] * 0.0625f;
            e = s * __builtin_amdgcn_rcpf(1.0f + fabsf(s));
            if (jg1 > ig || jg1 < ig - WIN) e = 0.0f;
            e1[r] = e;
        }
        dsacc += e0[0] * st0.x + e0[1] * st0.y + e0[2] * st0.z + e0[3] * st0.w
               + e1[0] * st1.x + e1[1] * st1.y + e1[2] * st1.z + e1[3] * st1.w;
        v4i pw;
        pw.x = pk2bf(e0[0], e0[1]);
        pw.y = pk2bf(e0[2], e0[3]);
        pw.z = pk2bf(e1[0], e1[1]);
        pw.w = pk2bf(e1[2], e1[3]);
        const bf16x8 pa = __builtin_bit_cast(bf16x8, pw);

        // ---- PV: 8 d-subtiles (this wave's d-half), B via tr_reads at j-blocks l4, l4+4 ----
        const unsigned lds_base = (unsigned)(size_t)bp;
        #pragma unroll
        for (int g = 0; g < 2; ++g) {
            v2i tr[8];
            #pragma unroll
            for (int tt = 0; tt < 4; ++tt) {
                const int nt = (jt << 3) + (g << 2) + tt;
                unsigned a0a = lds_base + (unsigned)((l4 << 11) + (nt << 7) + (l15 << 3));
                asm volatile("ds_read_b64_tr_b16 %0, %1" : "=v"(tr[2 * tt]) : "v"(a0a) : "memory");
                asm volatile("ds_read_b64_tr_b16 %0, %1 offset:8192" : "=v"(tr[2 * tt + 1]) : "v"(a0a) : "memory");
            }
            asm volatile("s_waitcnt lgkmcnt(0)" ::: "memory");
            __builtin_amdgcn_sched_barrier(0);
            #pragma unroll
            for (int tt = 0; tt < 4; ++tt) {
                v4i tmp;
                tmp.x = tr[2 * tt].x;     tmp.y = tr[2 * tt].y;
                tmp.z = tr[2 * tt + 1].x; tmp.w = tr[2 * tt + 1].y;
                bf16x8 bfr = __builtin_bit_cast(bf16x8, tmp);
                accpv[(g << 2) + tt] =
                    __builtin_amdgcn_mfma_f32_16x16x32_bf16(pa, bfr, accpv[(g << 2) + tt], 0, 0, 0);
            }
        }
        __syncthreads();   // single barrier: bn visible; bp reads done before re-stage
        p ^= 1;
    }

    // ---- delta_state: sum over l4 groups (same i), lane-local already has 8-j dot ----
    dsacc += __shfl_xor(dsacc, 16, 64);
    dsacc += __shfl_xor(dsacc, 32, 64);
    if (jt == 0 && l < 16)
        out_state[r0 + (mt << 4) + l15] = dsacc;

    // ---- delta_val epilogue: C layout col=lane&15 (d), row=l4*4+r (i) ----
    #pragma unroll
    for (int g = 0; g < 2; ++g) {
        #pragma unroll
        for (int tt = 0; tt < 4; ++tt) {
            const int nt = (jt << 3) + (g << 2) + tt;
            const int d  = (nt << 4) + l15;
            #pragma unroll
            for (int r = 0; r < 4; ++r) {
                const int ig2 = r0 + (mt << 4) + (l4 << 2) + r;
                out_val[(size_t)ig2 * DIM + d] = accpv[(g << 2) + tt][r];
            }
        }
    }
}

extern "C" void kernel_launch(void* const* d_in, const int* in_sizes, int n_in,
                              void* d_out, int out_size, void* d_ws, size_t ws_size,
                              hipStream_t stream) {
    const float* val   = (const float*)d_in[0];
    const float* state = (const float*)d_in[1];
    float* out = (float*)d_out;
    sp_kernel<<<dim3(BATCH * (NSEQ / 32)), dim3(256), 0, stream>>>(val, state, out);
}

// Round 12
// 16.790 us; speedup vs baseline: 1.1410x; 1.1410x over previous
//
#include <hip/hip_runtime.h>

#define NSEQ 4096
#define DIM  256
#define WIN  128
#define BATCH 4

typedef __bf16 bf16x8 __attribute__((ext_vector_type(8)));
typedef float  f32x4  __attribute__((ext_vector_type(4)));
typedef int    v2i    __attribute__((ext_vector_type(2)));
typedef int    v4i    __attribute__((ext_vector_type(4)));

// subtiled layout: element (j,d) of a 32x256 tile at
// ((j>>2)*16 + (d>>4))*64 + (j&3)*16 + (d&15)  halfwords. (verified r2-r10)
__device__ __forceinline__ int sub_off(int j, int d) {
    return (((j >> 2) * 16 + (d >> 4)) << 6) + ((j & 3) << 4) + (d & 15);
}

__device__ __forceinline__ unsigned short f2bf(float f) {
    unsigned u = __builtin_bit_cast(unsigned, f);
    u += 0x7fffu + ((u >> 16) & 1u);   // RNE
    return (unsigned short)(u >> 16);
}

// HW packed f32->bf16 (RNE)
__device__ __forceinline__ unsigned pk2bf(float lo, float hi) {
    unsigned r;
    asm("v_cvt_pk_bf16_f32 %0, %1, %2" : "=v"(r) : "v"(lo), "v"(hi));
    return r;
}

__global__ __launch_bounds__(512, 2)   // 8 waves, 1 block/CU (LDS 111 KB), VGPR cap 256
void sp_kernel(const float* __restrict__ val,
               const float* __restrict__ state,
               float* __restrict__ out) {
    __shared__ __align__(128) unsigned short W[6 * 8192];     // 96 KB: whole j-window
    __shared__ __align__(128) unsigned short E_s[2][64 * 56]; // 14 KB parity dbuf
    __shared__ float ds_part[8][16];

    // XCD-aware bijective swizzle (256 = 8*32): neighbors share window rows -> same XCD L2
    const int bx  = blockIdx.x;
    const int lbx = ((bx & 7) << 5) + (bx >> 3);
    const int b   = lbx >> 6;          // 64 blocks per batch
    const int i0  = (lbx & 63) << 6;   // BR = 64
    const int Ti  = (lbx & 63) << 1;   // first i-tile (32-row units)

    const int t   = threadIdx.x;
    const int w   = t >> 6;            // 0..7
    const int l   = t & 63;
    const int l15 = l & 15;
    const int l4  = l >> 4;
    const int mt  = w >> 1;            // i-quarter (0..3)
    const int jt  = w & 1;             // j-half (0..1)

    const float* valb = val + ((size_t)b * NSEQ) * DIM;
    const float* stb  = state + ((size_t)b * NSEQ);
    float* out_state  = out + ((size_t)b * NSEQ);
    float* out_val    = out + (size_t)BATCH * NSEQ + ((size_t)b * NSEQ) * DIM;

    const int Tj0   = (Ti >= 4) ? (Ti - 4) : 0;
    const int ntile = Ti + 2 - Tj0;    // 2..6 j-tiles in window

    // ---- prologue: stage the whole window once (half h stages slots h, h+2, h+4) ----
    {
        const int hh = t >> 8;
        const int w4 = (t >> 6) & 3;
        const int s_jl0 = (w4 << 2) + l4;      // r2-verified conflict pattern
        const int s_jl1 = s_jl0 + 16;
        for (int k = 0; k < 3; ++k) {
            const int s = hh + (k << 1);
            if (s < ntile) {
                const float* src = valb + ((size_t)(Tj0 + s) << 13);
                unsigned short* dst = &W[s << 13];
                #pragma unroll
                for (int qq = 0; qq < 8; ++qq) {
                    const int jl = (qq & 1) ? s_jl1 : s_jl0;
                    const int d0 = (l15 << 2) + ((qq >> 1) << 6);
                    float4 v = *reinterpret_cast<const float4*>(src + jl * DIM + d0);
                    uint2 u;
                    u.x = pk2bf(v.x, v.y);
                    u.y = pk2bf(v.z, v.w);
                    *reinterpret_cast<uint2*>(&dst[sub_off(jl, d0)]) = u;
                }
            }
        }
    }
    __syncthreads();

    // ---- af: Vi rows for this wave's i-quarter (Vi = last two window slots) ----
    const int slotVi = ntile - 2 + (mt >> 1);
    const int ilr    = ((mt & 1) << 4) + l15;
    bf16x8 af[8];
    #pragma unroll
    for (int ks = 0; ks < 8; ++ks)
        af[ks] = *reinterpret_cast<const bf16x8*>(&W[(slotVi << 13) + sub_off(ilr, (l4 << 3) + (ks << 5))]);

    float dsacc[4] = {0.f, 0.f, 0.f, 0.f};
    f32x4 accpv[4][2];
    #pragma unroll
    for (int q = 0; q < 4; ++q)
        #pragma unroll
        for (int u = 0; u < 2; ++u)
            accpv[q][u] = (f32x4){0.f, 0.f, 0.f, 0.f};

    // ---- main loop: one barrier per j-tile; window is read-only ----
    for (int s = 0; s < ntile; ++s) {
        const int jb = (Tj0 + s) << 5;
        const unsigned short* bp = &W[s << 13];
        unsigned short* Ec = &E_s[s & 1][0];

        // scores: S quadrant (mt i-quarter x jt j-half), K=256
        bf16x8 sb[8];
        #pragma unroll
        for (int ks = 0; ks < 8; ++ks)
            sb[ks] = *reinterpret_cast<const bf16x8*>(&bp[sub_off((jt << 4) + l15, (l4 << 3) + (ks << 5))]);
        f32x4 acc = (f32x4){0.f, 0.f, 0.f, 0.f};
        __builtin_amdgcn_s_setprio(1);
        #pragma unroll
        for (int ks = 0; ks < 8; ++ks)
            acc = __builtin_amdgcn_mfma_f32_16x16x32_bf16(af[ks], sb[ks], acc, 0, 0, 0);
        __builtin_amdgcn_s_setprio(0);

        // edges: scale, softsign, mask; dsacc; E write (C: col=l15 -> j, row=l4*4+r -> i)
        const int jg = jb + (jt << 4) + l15;
        const float stv = stb[jg];
        #pragma unroll
        for (int r = 0; r < 4; ++r) {
            const int irow = (mt << 4) + (l4 << 2) + r;
            const int ig   = i0 + irow;
            float sv = acc[r] * 0.0625f;       // / sqrt(256)
            float e  = sv * __builtin_amdgcn_rcpf(1.0f + fabsf(sv));
            if (jg > ig || jg < ig - WIN) e = 0.0f;
            dsacc[r] += e * stv;
            Ec[irow * 56 + (jt << 4) + l15] = f2bf(e);
        }
        __syncthreads();   // E quadrant complete; (E[(s+1)&1] untouched by racers)

        // PV: ef rows (4 i-quarters), tr-reads for this wave's 2 d-subtiles, 8 MFMAs
        bf16x8 ef[4];
        #pragma unroll
        for (int q = 0; q < 4; ++q)
            ef[q] = *reinterpret_cast<const bf16x8*>(&Ec[((q << 4) + l15) * 56 + (l4 << 3)]);
        const unsigned lds_base = (unsigned)(size_t)bp;
        v2i tr[4];
        #pragma unroll
        for (int u = 0; u < 2; ++u) {
            const int nt = (w << 1) + u;       // d-subtile 0..15
            unsigned a0 = lds_base + (unsigned)((((l4 << 5) + nt) << 7) + (l15 << 3));
            asm volatile("ds_read_b64_tr_b16 %0, %1" : "=v"(tr[2 * u]) : "v"(a0) : "memory");
            asm volatile("ds_read_b64_tr_b16 %0, %1 offset:2048" : "=v"(tr[2 * u + 1]) : "v"(a0) : "memory");
        }
        asm volatile("s_waitcnt lgkmcnt(0)" ::: "memory");
        __builtin_amdgcn_sched_barrier(0);
        __builtin_amdgcn_s_setprio(1);
        #pragma unroll
        for (int u = 0; u < 2; ++u) {
            v4i tmp;
            tmp.x = tr[2 * u].x;     tmp.y = tr[2 * u].y;
            tmp.z = tr[2 * u + 1].x; tmp.w = tr[2 * u + 1].y;
            bf16x8 bfr = __builtin_bit_cast(bf16x8, tmp);
            #pragma unroll
            for (int q = 0; q < 4; ++q)
                accpv[q][u] = __builtin_amdgcn_mfma_f32_16x16x32_bf16(ef[q], bfr, accpv[q][u], 0, 0, 0);
        }
        __builtin_amdgcn_s_setprio(0);
    }

    // ---- delta_state: reduce over j (l15 dim), combine jt-halves via LDS ----
    #pragma unroll
    for (int m = 1; m <= 8; m <<= 1) {
        #pragma unroll
        for (int r = 0; r < 4; ++r)
            dsacc[r] += __shfl_xor(dsacc[r], m, 64);
    }
    if (l15 == 0) {
        #pragma unroll
        for (int r = 0; r < 4; ++r)
            ds_part[w][(l4 << 2) + r] = dsacc[r];
    }
    __syncthreads();
    if (t < 64)
        out_state[i0 + t] = ds_part[(t >> 4) << 1][t & 15] + ds_part[((t >> 4) << 1) + 1][t & 15];

    // ---- delta_val epilogue: C layout col=l15 (d), row=l4*4+r (i); wave owns d [32w,32w+32) ----
    #pragma unroll
    for (int q = 0; q < 4; ++q) {
        #pragma unroll
        for (int u = 0; u < 2; ++u) {
            const int d = (((w << 1) + u) << 4) + l15;
            #pragma unroll
            for (int r = 0; r < 4; ++r) {
                const int ig = i0 + (q << 4) + (l4 << 2) + r;
                out_val[(size_t)ig * DIM + d] = accpv[q][u][r];
            }
        }
    }
}

extern "C" void kernel_launch(void* const* d_in, const int* in_sizes, int n_in,
                              void* d_out, int out_size, void* d_ws, size_t ws_size,
                              hipStream_t stream) {
    const float* val   = (const float*)d_in[0];
    const float* state = (const float*)d_in[1];
    float* out = (float*)d_out;
    sp_kernel<<<dim3(BATCH * (NSEQ / 64)), dim3(512), 0, stream>>>(val, state, out);
}